// Round 4
// baseline (199.699 us; speedup 1.0000x reference)
//
#include <hip/hip_runtime.h>
#include <math.h>

// Problem constants
static constexpr int Bn   = 32;
static constexpr int Tn   = 512;
static constexpr int Cn   = 128;
static constexpr int Kk   = 3;
static constexpr int NLAG = 57;   // lags 8..64 inclusive
static constexpr int CYC  = 64;   // CYC_MAX
static constexpr int KWn  = 9;

// ---------------------------------------------------------------------------
// Inline top-3 scan over summed autocorr partials. Data-uniform across all
// threads of a block -> scalar branches, no divergence. Strict > keeps the
// first-max (lax.top_k stable tie rule).
// ---------------------------------------------------------------------------
__device__ __forceinline__ void topk_scan(const float* __restrict__ r_ws, int b,
    int& p0, int& p1, int& p2, float& w0, float& w1, float& w2, float& Gv) {
  const float* r0 = r_ws + (size_t)(b * 4 + 0) * NLAG;
  const float* r1 = r_ws + (size_t)(b * 4 + 1) * NLAG;
  const float* r2 = r_ws + (size_t)(b * 4 + 2) * NLAG;
  const float* r3 = r_ws + (size_t)(b * 4 + 3) * NLAG;
  float v0 = -INFINITY, v1 = -INFINITY, v2 = -INFINITY;
  int i0 = 0, i1 = 0, i2 = 0;
  for (int i = 0; i < NLAG; ++i) {
    const float v = r0[i] + r1[i] + r2[i] + r3[i];
    if (v > v0)      { v2 = v1; i2 = i1; v1 = v0; i1 = i0; v0 = v; i0 = i; }
    else if (v > v1) { v2 = v1; i2 = i1; v1 = v; i1 = i; }
    else if (v > v2) { v2 = v; i2 = i; }
  }
  p0 = i0 + 8; p1 = i1 + 8; p2 = i2 + 8;
  const float e1 = expf(v1 - v0), e2 = expf(v2 - v0);
  const float s = 1.0f + e1 + e2;
  w0 = 1.0f / s; w1 = e1 / s; w2 = e2 / s;
  const float H  = -(w0 * logf(w0 + 1e-8f) + w1 * logf(w1 + 1e-8f) + w2 * logf(w2 + 1e-8f));
  const float lg = logf(3.0f + 1e-8f) + 1e-8f;
  Gv = fminf(fmaxf(1.0f - H / lg, 0.0f), 1.0f);
}

// ---------------------------------------------------------------------------
// K1: autocorr partials. Block = (b, lag-group of 8, t-quarter). 1024 blocks
// -> ~4 blocks/CU so the L2-latency + fma chain is TLP-hidden (R3: 1 wave/SIMD).
// ---------------------------------------------------------------------------
__global__ __launch_bounds__(256, 3) void k_autocorr(const float* __restrict__ x,
    float* __restrict__ r_ws) {
  const int bk  = blockIdx.x;
  const int b   = bk >> 5;
  const int grp = (bk >> 2) & 7;
  const int th  = bk & 3;
  const int L0  = 8 + grp * 8;
  const int tid = threadIdx.x;
  const float4* X4 = (const float4*)(x + (size_t)b * Tn * Cn);  // [512][32]

  float acc[8];
#pragma unroll
  for (int i = 0; i < 8; ++i) acc[i] = 0.f;

#pragma unroll
  for (int s = 0; s < 2; ++s) {              // this block's 2 of the 8 it-slices
    const int id = (th * 2 + s) * 256 + tid;
    const int c4 = id & 31;
    const int t0 = (id >> 5) * 8;
    float4 A[8];
#pragma unroll
    for (int j = 0; j < 8; ++j) A[j] = X4[(t0 + j) * 32 + c4];
    float4 R[16];
#pragma unroll
    for (int j = 0; j < 16; ++j) R[j] = X4[((t0 + L0 + j) & 511) * 32 + c4];
#pragma unroll
    for (int g = 0; g < 8; ++g) {
#pragma unroll
      for (int j = 0; j < 8; ++j) {
        const float4 a = A[j];
        const float4 r = R[g + j];
        acc[g] += a.x * r.x + a.y * r.y + a.z * r.z + a.w * r.w;
      }
    }
  }

  __shared__ float lds_r[4][8];
  const int lane = tid & 63, wave = tid >> 6;
#pragma unroll
  for (int g = 0; g < 8; ++g) {
    float v = acc[g];
#pragma unroll
    for (int m = 32; m > 0; m >>= 1) v += __shfl_xor(v, m, 64);
    if (lane == 0) lds_r[wave][g] = v;
  }
  __syncthreads();
  if (tid < 8) {
    const int li = grp * 8 + tid;
    if (li < NLAG) {
      r_ws[(size_t)(b * 4 + th) * NLAG + li] =
          (lds_r[0][tid] + lds_r[1][tid] + lds_r[2][tid] + lds_r[3][tid]) * (1.0f / Cn);
    }
  }
}

// ---------------------------------------------------------------------------
// K2: fused fold + dwconv + pointwise + GN + gelu + gate.
// grid (n=96, og=8); block builds its own u-tile in LDS from x (no u buffer,
// no separate fold kernel). 16 outputs = 4 self-contained GN groups.
// ---------------------------------------------------------------------------
__global__ __launch_bounds__(256) void k_foldconv(const float* __restrict__ x,
    const float* __restrict__ r_ws, const float* __restrict__ Wdw,
    const float* __restrict__ Wpw, const float* __restrict__ gnw,
    const float* __restrict__ gnb, const float* __restrict__ Wgate,
    float* __restrict__ hh) {
  const int n  = blockIdx.x;
  const int og = blockIdx.y;
  const int b  = n / 3;
  const int kk = n - b * 3;
  const int tid = threadIdx.x;
  const int l  = tid & 63;

  int p0, p1, p2; float w0, w1, w2, Gv;
  topk_scan(r_ws, b, p0, p1, p2, w0, w1, w2, Gv);
  const int p = (kk == 0) ? p0 : ((kk == 1) ? p1 : p2);
  const int ncyc = (Tn + p - 1) / p;

  __shared__ float smem[8320];     // u-view: [64][129]; h1-view: [128][65]
  __shared__ float ubar_s[Cn];
  __shared__ float gates_s[16];

  // fold: u[l][c] = (1/64) sum_{j<p} x[refl(l*p+j)][c]; zeros for l>=ncyc
  const float4* X4 = (const float4*)(x + (size_t)b * Tn * Cn);
  for (int it = 0; it < 8; ++it) {
    const int id = it * 256 + tid;
    const int c4 = id & 31;
    const int ll = id >> 5;
    float sx = 0.f, sy = 0.f, sz = 0.f, sw2 = 0.f;
    if (ll < ncyc) {
      const int base = ll * p;
      for (int j = 0; j < p; ++j) {
        const int time = base + j;                        // <= 575
        const int src = time < Tn ? time : (2 * (Tn - 1) - time);
        const float4 a = X4[src * 32 + c4];
        sx += a.x; sy += a.y; sz += a.z; sw2 += a.w;
      }
    }
    const int adr = ll * 129 + c4 * 4;
    smem[adr + 0] = sx * (1.0f / 64.0f);
    smem[adr + 1] = sy * (1.0f / 64.0f);
    smem[adr + 2] = sz * (1.0f / 64.0f);
    smem[adr + 3] = sw2 * (1.0f / 64.0f);
  }
  __syncthreads();

  // ubar over all 64 l (matches reference: mean includes zero rows)
  if (tid < Cn) {
    float s = 0.f;
    for (int ll = 0; ll < CYC; ++ll) s += smem[ll * 129 + tid];
    ubar_s[tid] = s * (1.0f / CYC);
  }

  // depthwise conv -> registers (reads u-view)
  float hreg[32];
  const int c0 = (tid >> 6) * 32;
#pragma unroll
  for (int i = 0; i < 32; ++i) {
    const int c = c0 + i;
    float s = 0.f;
#pragma unroll
    for (int k2 = 0; k2 < KWn; ++k2) {
      const int ll = l + k2 - KWn / 2;
      if (ll >= 0 && ll < CYC) s += smem[ll * 129 + c] * Wdw[c * KWn + k2];
    }
    hreg[i] = s;
  }
  __syncthreads();   // u-view reads complete; ubar_s published

  // overwrite LDS with h1-view [c][65]; gates from ubar_s
#pragma unroll
  for (int i = 0; i < 32; ++i) smem[(c0 + i) * 65 + l] = hreg[i];
  if (tid < 16) {
    const int o = og * 16 + tid;
    float z = 0.f;
    for (int c = 0; c < Cn; ++c) z += Wgate[o * Cn + c] * ubar_s[c];
    gates_s[tid] = 1.0f / (1.0f + expf(-z));
  }
  __syncthreads();

  // pointwise: 4 outputs per wave (Wpw rows wave-uniform -> s_loads)
  const int o4 = og * 16 + (tid >> 6) * 4;
  float acc[4] = {0.f, 0.f, 0.f, 0.f};
  const float* wb = Wpw + (size_t)o4 * Cn;
  for (int c = 0; c < Cn; ++c) {
    const float hv = smem[c * 65 + l];
#pragma unroll
    for (int i = 0; i < 4; ++i) acc[i] = fmaf(wb[i * Cn + c], hv, acc[i]);
  }

  // GroupNorm: wave's 4 o == one GN group (4 ch x 64 l)
  float s1 = acc[0] + acc[1] + acc[2] + acc[3];
  float s2 = acc[0]*acc[0] + acc[1]*acc[1] + acc[2]*acc[2] + acc[3]*acc[3];
#pragma unroll
  for (int m = 32; m > 0; m >>= 1) {
    s1 += __shfl_xor(s1, m, 64);
    s2 += __shfl_xor(s2, m, 64);
  }
  const float mean = s1 * (1.0f / 256.0f);
  const float var  = s2 * (1.0f / 256.0f) - mean * mean;
  const float rstd = rsqrtf(var + 1e-5f);

  float4 res;
  float* rp = (float*)&res;
#pragma unroll
  for (int i = 0; i < 4; ++i) {
    const int o = o4 + i;
    float h = (acc[i] - mean) * rstd;
    h = h * gnw[o] + gnb[o];
    h = 0.5f * h * (1.0f + erff(h * 0.70710678118654752440f));
    rp[i] = h * gates_s[o - og * 16];
  }
  *(float4*)(hh + ((size_t)n * CYC + l) * Cn + o4) = res;
}

// ---------------------------------------------------------------------------
// K3: partial num/den per (b, c) over t-chunk of 64. grid (q=8, b=32).
// ---------------------------------------------------------------------------
__global__ __launch_bounds__(128) void k_dot(const float* __restrict__ x,
    const float* __restrict__ hh, const float* __restrict__ r_ws,
    const float* __restrict__ gamma, float* __restrict__ pna,
    float* __restrict__ pda) {
  const int q = blockIdx.x, b = blockIdx.y;
  const int tid = threadIdx.x;
  const int t0 = q * 64;
  __shared__ unsigned short cycs[64][4];

  int p0, p1, p2; float w0, w1, w2, Gv;
  topk_scan(r_ws, b, p0, p1, p2, w0, w1, w2, Gv);
  const float sw = w0 + w1 + w2;
  if (tid < 64) {
    const int t = t0 + tid;
    cycs[tid][0] = (unsigned short)(t / p0);
    cycs[tid][1] = (unsigned short)(t / p1);
    cycs[tid][2] = (unsigned short)(t / p2);
  }
  __syncthreads();

  const int c = tid;
  const float gam = gamma[c];
  const float* hh0 = hh + ((size_t)(b * 3 + 0) * CYC) * Cn + c;
  const float* hh1 = hh + ((size_t)(b * 3 + 1) * CYC) * Cn + c;
  const float* hh2 = hh + ((size_t)(b * 3 + 2) * CYC) * Cn + c;
  const float* xb = x + (size_t)b * Tn * Cn;

  float na = 0.f, da = 0.f;
  for (int tt = 0; tt < 64; ++tt) {
    const int t = t0 + tt;
    const float xv = xb[t * Cn + c];
    const float dv = gam * (w0 * hh0[cycs[tt][0] * Cn] +
                            w1 * hh1[cycs[tt][1] * Cn] +
                            w2 * hh2[cycs[tt][2] * Cn]);
    const float P = sw * xv + dv;
    na += (xv - P) * P;
    da += P * P;
  }
  pna[((size_t)b * 8 + q) * Cn + c] = na;
  pda[((size_t)b * 8 + q) * Cn + c] = da;
}

// ---------------------------------------------------------------------------
// K4: reduce partials, write out. grid (q=8, b=32).
// ---------------------------------------------------------------------------
__global__ __launch_bounds__(128) void k_out(const float* __restrict__ x,
    const float* __restrict__ hh, const float* __restrict__ r_ws,
    const float* __restrict__ gamma, const float* __restrict__ pna,
    const float* __restrict__ pda, float* __restrict__ out) {
  const int q = blockIdx.x, b = blockIdx.y;
  const int tid = threadIdx.x;
  const int t0 = q * 64;
  __shared__ unsigned short cycs[64][4];

  int p0, p1, p2; float w0, w1, w2, Gv;
  topk_scan(r_ws, b, p0, p1, p2, w0, w1, w2, Gv);
  const float sw = w0 + w1 + w2;
  if (tid < 64) {
    const int t = t0 + tid;
    cycs[tid][0] = (unsigned short)(t / p0);
    cycs[tid][1] = (unsigned short)(t / p1);
    cycs[tid][2] = (unsigned short)(t / p2);
  }
  __syncthreads();

  const int c = tid;
  float num = 0.f, den = 1e-6f;
#pragma unroll
  for (int qq = 0; qq < 8; ++qq) {
    num += pna[((size_t)b * 8 + qq) * Cn + c];
    den += pda[((size_t)b * 8 + qq) * Cn + c];
  }
  const float sc = Gv * (num / den);

  const float gam = gamma[c];
  const float* hh0 = hh + ((size_t)(b * 3 + 0) * CYC) * Cn + c;
  const float* hh1 = hh + ((size_t)(b * 3 + 1) * CYC) * Cn + c;
  const float* hh2 = hh + ((size_t)(b * 3 + 2) * CYC) * Cn + c;
  const float* xb = x + (size_t)b * Tn * Cn;
  float* ob = out + (size_t)b * Tn * Cn;

  for (int tt = 0; tt < 64; ++tt) {
    const int t = t0 + tt;
    const float xv = xb[t * Cn + c];
    const float dv = gam * (w0 * hh0[cycs[tt][0] * Cn] +
                            w1 * hh1[cycs[tt][1] * Cn] +
                            w2 * hh2[cycs[tt][2] * Cn]);
    const float P = sw * xv + dv;
    ob[t * Cn + c] = xv - sc * P;
  }
}

// ---------------------------------------------------------------------------
extern "C" void kernel_launch(void* const* d_in, const int* in_sizes, int n_in,
                              void* d_out, int out_size, void* d_ws, size_t ws_size,
                              hipStream_t stream) {
  const float* x     = (const float*)d_in[0];
  const float* Wdw   = (const float*)d_in[1];
  const float* Wpw   = (const float*)d_in[2];
  const float* gnw   = (const float*)d_in[3];
  const float* gnb   = (const float*)d_in[4];
  const float* Wgate = (const float*)d_in[5];
  const float* gamma = (const float*)d_in[6];
  float* out = (float*)d_out;

  char* ws = (char*)d_ws;
  float* r_ws = (float*)ws;                       // 32*4*57 floats (~29 KB)
  float* pna  = (float*)(ws + 65536);             // 32*8*128 floats (128 KB)
  float* pda  = (float*)(ws + 65536 + 131072);    // 128 KB
  float* hh   = (float*)(ws + 1048576);           // 96*64*128 floats (3 MB)

  k_autocorr<<<Bn * 32, 256, 0, stream>>>(x, r_ws);
  k_foldconv<<<dim3(Bn * Kk, 8), 256, 0, stream>>>(x, r_ws, Wdw, Wpw, gnw, gnb, Wgate, hh);
  k_dot<<<dim3(8, Bn), 128, 0, stream>>>(x, hh, r_ws, gamma, pna, pda);
  k_out<<<dim3(8, Bn), 128, 0, stream>>>(x, hh, r_ws, gamma, pna, pda, out);
}

// Round 5
// 182.777 us; speedup vs baseline: 1.0926x; 1.0926x over previous
//
#include <hip/hip_runtime.h>
#include <math.h>

// Problem constants
static constexpr int Bn   = 32;
static constexpr int Tn   = 512;
static constexpr int Cn   = 128;
static constexpr int Kk   = 3;
static constexpr int NLAG = 57;   // lags 8..64 inclusive
static constexpr int CYC  = 64;   // CYC_MAX
static constexpr int KWn  = 9;

// ---------------------------------------------------------------------------
// Inline top-3 scan over summed autocorr partials (data-uniform, no divergence).
// ---------------------------------------------------------------------------
__device__ __forceinline__ void topk_scan(const float* __restrict__ r_ws, int b,
    int& p0, int& p1, int& p2, float& w0, float& w1, float& w2, float& Gv) {
  const float* r0 = r_ws + (size_t)(b * 4 + 0) * NLAG;
  const float* r1 = r_ws + (size_t)(b * 4 + 1) * NLAG;
  const float* r2 = r_ws + (size_t)(b * 4 + 2) * NLAG;
  const float* r3 = r_ws + (size_t)(b * 4 + 3) * NLAG;
  float v0 = -INFINITY, v1 = -INFINITY, v2 = -INFINITY;
  int i0 = 0, i1 = 0, i2 = 0;
  for (int i = 0; i < NLAG; ++i) {
    const float v = r0[i] + r1[i] + r2[i] + r3[i];
    if (v > v0)      { v2 = v1; i2 = i1; v1 = v0; i1 = i0; v0 = v; i0 = i; }
    else if (v > v1) { v2 = v1; i2 = i1; v1 = v; i1 = i; }
    else if (v > v2) { v2 = v; i2 = i; }
  }
  p0 = i0 + 8; p1 = i1 + 8; p2 = i2 + 8;
  const float e1 = expf(v1 - v0), e2 = expf(v2 - v0);
  const float s = 1.0f + e1 + e2;
  w0 = 1.0f / s; w1 = e1 / s; w2 = e2 / s;
  const float H  = -(w0 * logf(w0 + 1e-8f) + w1 * logf(w1 + 1e-8f) + w2 * logf(w2 + 1e-8f));
  const float lg = logf(3.0f + 1e-8f) + 1e-8f;
  Gv = fminf(fmaxf(1.0f - H / lg, 0.0f), 1.0f);
}

// ---------------------------------------------------------------------------
// K1: autocorr partials. Block = (b, lag-group of 8, t-quarter). 1024 blocks.
// ---------------------------------------------------------------------------
__global__ __launch_bounds__(256, 3) void k_autocorr(const float* __restrict__ x,
    float* __restrict__ r_ws) {
  const int bk  = blockIdx.x;
  const int b   = bk >> 5;
  const int grp = (bk >> 2) & 7;
  const int th  = bk & 3;
  const int L0  = 8 + grp * 8;
  const int tid = threadIdx.x;
  const float4* X4 = (const float4*)(x + (size_t)b * Tn * Cn);  // [512][32]

  float acc[8];
#pragma unroll
  for (int i = 0; i < 8; ++i) acc[i] = 0.f;

#pragma unroll
  for (int s = 0; s < 2; ++s) {
    const int id = (th * 2 + s) * 256 + tid;
    const int c4 = id & 31;
    const int t0 = (id >> 5) * 8;
    float4 A[8];
#pragma unroll
    for (int j = 0; j < 8; ++j) A[j] = X4[(t0 + j) * 32 + c4];
    float4 R[16];
#pragma unroll
    for (int j = 0; j < 16; ++j) R[j] = X4[((t0 + L0 + j) & 511) * 32 + c4];
#pragma unroll
    for (int g = 0; g < 8; ++g) {
#pragma unroll
      for (int j = 0; j < 8; ++j) {
        const float4 a = A[j];
        const float4 r = R[g + j];
        acc[g] += a.x * r.x + a.y * r.y + a.z * r.z + a.w * r.w;
      }
    }
  }

  __shared__ float lds_r[4][8];
  const int lane = tid & 63, wave = tid >> 6;
#pragma unroll
  for (int g = 0; g < 8; ++g) {
    float v = acc[g];
#pragma unroll
    for (int m = 32; m > 0; m >>= 1) v += __shfl_xor(v, m, 64);
    if (lane == 0) lds_r[wave][g] = v;
  }
  __syncthreads();
  if (tid < 8) {
    const int li = grp * 8 + tid;
    if (li < NLAG) {
      r_ws[(size_t)(b * 4 + th) * NLAG + li] =
          (lds_r[0][tid] + lds_r[1][tid] + lds_r[2][tid] + lds_r[3][tid]) * (1.0f / Cn);
    }
  }
}

// ---------------------------------------------------------------------------
// K2 v3: fused fold + dwconv + pointwise + GN + gelu + gate.
// grid (n=96, og=2), 512 threads (8 waves). Fold redundancy x2 (was x8 in R4
// -> 78us; fold is a fixed per-block cost, so og-split multiplies it).
// Block computes 64 outputs = 16 self-contained GN groups; 8 o per wave.
// ---------------------------------------------------------------------------
__global__ __launch_bounds__(512) void k_foldconv(const float* __restrict__ x,
    const float* __restrict__ r_ws, const float* __restrict__ Wdw,
    const float* __restrict__ Wpw, const float* __restrict__ gnw,
    const float* __restrict__ gnb, const float* __restrict__ Wgate,
    float* __restrict__ hh) {
  const int n  = blockIdx.x;
  const int og = blockIdx.y;           // 0 or 1 -> outputs og*64 .. +64
  const int b  = n / 3;
  const int kk = n - b * 3;
  const int tid = threadIdx.x;
  const int l  = tid & 63;
  const int w  = tid >> 6;             // wave 0..7

  int p0, p1, p2; float w0, w1, w2, Gv;
  topk_scan(r_ws, b, p0, p1, p2, w0, w1, w2, Gv);
  const int p = (kk == 0) ? p0 : ((kk == 1) ? p1 : p2);
  const int ncyc = (Tn + p - 1) / p;

  __shared__ float smem[8320];         // u-view: [64][129]; h1-view: [128][65]
  __shared__ float ubar_s[Cn];
  __shared__ float gates_s[64];

  // fold: u[ll][c] = (1/64) sum_{j<p} x[refl(ll*p+j)][c]; zeros for ll>=ncyc
  const float4* X4 = (const float4*)(x + (size_t)b * Tn * Cn);
  for (int it = 0; it < 4; ++it) {
    const int id = it * 512 + tid;
    const int c4 = id & 31;
    const int ll = id >> 5;
    float sx = 0.f, sy = 0.f, sz = 0.f, sw2 = 0.f;
    if (ll < ncyc) {
      const int base = ll * p;
      for (int j = 0; j < p; ++j) {
        const int time = base + j;                        // <= 575
        const int src = time < Tn ? time : (2 * (Tn - 1) - time);
        const float4 a = X4[src * 32 + c4];
        sx += a.x; sy += a.y; sz += a.z; sw2 += a.w;
      }
    }
    const int adr = ll * 129 + c4 * 4;
    smem[adr + 0] = sx * (1.0f / 64.0f);
    smem[adr + 1] = sy * (1.0f / 64.0f);
    smem[adr + 2] = sz * (1.0f / 64.0f);
    smem[adr + 3] = sw2 * (1.0f / 64.0f);
  }
  __syncthreads();

  // ubar over all 64 l (threads 0..127)
  if (tid < Cn) {
    float s = 0.f;
    for (int ll = 0; ll < CYC; ++ll) s += smem[ll * 129 + tid];
    ubar_s[tid] = s * (1.0f / CYC);
  }

  // depthwise conv -> registers: wave w covers c = w*16 .. +16, lane = l
  float hreg[16];
  const int c0 = w * 16;
#pragma unroll
  for (int i = 0; i < 16; ++i) {
    const int c = c0 + i;
    float s = 0.f;
#pragma unroll
    for (int k2 = 0; k2 < KWn; ++k2) {
      const int ll = l + k2 - KWn / 2;
      if (ll >= 0 && ll < CYC) s += smem[ll * 129 + c] * Wdw[c * KWn + k2];
    }
    hreg[i] = s;
  }
  __syncthreads();   // u-view reads complete; ubar_s published

  // overwrite LDS with h1-view [c][65]; gates for this block's 64 outputs
#pragma unroll
  for (int i = 0; i < 16; ++i) smem[(c0 + i) * 65 + l] = hreg[i];
  if (tid < 64) {
    const int o = og * 64 + tid;
    float z = 0.f;
    for (int c = 0; c < Cn; ++c) z += Wgate[o * Cn + c] * ubar_s[c];
    gates_s[tid] = 1.0f / (1.0f + expf(-z));
  }
  __syncthreads();

  // pointwise: 8 outputs per wave (Wpw rows wave-uniform -> s_loads)
  const int o8 = og * 64 + w * 8;
  float acc[8] = {0.f, 0.f, 0.f, 0.f, 0.f, 0.f, 0.f, 0.f};
  const float* wb = Wpw + (size_t)o8 * Cn;
  for (int c = 0; c < Cn; ++c) {
    const float hv = smem[c * 65 + l];
#pragma unroll
    for (int i = 0; i < 8; ++i) acc[i] = fmaf(wb[i * Cn + c], hv, acc[i]);
  }

  // GroupNorm: wave's 8 o == two GN groups (4 ch x 64 l each)
  float s1a = acc[0] + acc[1] + acc[2] + acc[3];
  float s2a = acc[0]*acc[0] + acc[1]*acc[1] + acc[2]*acc[2] + acc[3]*acc[3];
  float s1b = acc[4] + acc[5] + acc[6] + acc[7];
  float s2b = acc[4]*acc[4] + acc[5]*acc[5] + acc[6]*acc[6] + acc[7]*acc[7];
#pragma unroll
  for (int m = 32; m > 0; m >>= 1) {
    s1a += __shfl_xor(s1a, m, 64);
    s2a += __shfl_xor(s2a, m, 64);
    s1b += __shfl_xor(s1b, m, 64);
    s2b += __shfl_xor(s2b, m, 64);
  }
  const float mean_a = s1a * (1.0f / 256.0f);
  const float var_a  = s2a * (1.0f / 256.0f) - mean_a * mean_a;
  const float rstd_a = rsqrtf(var_a + 1e-5f);
  const float mean_b = s1b * (1.0f / 256.0f);
  const float var_b  = s2b * (1.0f / 256.0f) - mean_b * mean_b;
  const float rstd_b = rsqrtf(var_b + 1e-5f);

  float res[8];
#pragma unroll
  for (int i = 0; i < 8; ++i) {
    const int o = o8 + i;
    const float mean = (i < 4) ? mean_a : mean_b;
    const float rstd = (i < 4) ? rstd_a : rstd_b;
    float h = (acc[i] - mean) * rstd;
    h = h * gnw[o] + gnb[o];
    h = 0.5f * h * (1.0f + erff(h * 0.70710678118654752440f));
    res[i] = h * gates_s[o - og * 64];
  }
  float* base = hh + ((size_t)n * CYC + l) * Cn + o8;
  *(float4*)(base)     = make_float4(res[0], res[1], res[2], res[3]);
  *(float4*)(base + 4) = make_float4(res[4], res[5], res[6], res[7]);
}

// ---------------------------------------------------------------------------
// K3: partial num/den per (b, c) over t-chunk of 64. grid (q=8, b=32).
// ---------------------------------------------------------------------------
__global__ __launch_bounds__(128) void k_dot(const float* __restrict__ x,
    const float* __restrict__ hh, const float* __restrict__ r_ws,
    const float* __restrict__ gamma, float* __restrict__ pna,
    float* __restrict__ pda) {
  const int q = blockIdx.x, b = blockIdx.y;
  const int tid = threadIdx.x;
  const int t0 = q * 64;
  __shared__ unsigned short cycs[64][4];

  int p0, p1, p2; float w0, w1, w2, Gv;
  topk_scan(r_ws, b, p0, p1, p2, w0, w1, w2, Gv);
  const float sw = w0 + w1 + w2;
  if (tid < 64) {
    const int t = t0 + tid;
    cycs[tid][0] = (unsigned short)(t / p0);
    cycs[tid][1] = (unsigned short)(t / p1);
    cycs[tid][2] = (unsigned short)(t / p2);
  }
  __syncthreads();

  const int c = tid;
  const float gam = gamma[c];
  const float* hh0 = hh + ((size_t)(b * 3 + 0) * CYC) * Cn + c;
  const float* hh1 = hh + ((size_t)(b * 3 + 1) * CYC) * Cn + c;
  const float* hh2 = hh + ((size_t)(b * 3 + 2) * CYC) * Cn + c;
  const float* xb = x + (size_t)b * Tn * Cn;

  float na = 0.f, da = 0.f;
  for (int tt = 0; tt < 64; ++tt) {
    const int t = t0 + tt;
    const float xv = xb[t * Cn + c];
    const float dv = gam * (w0 * hh0[cycs[tt][0] * Cn] +
                            w1 * hh1[cycs[tt][1] * Cn] +
                            w2 * hh2[cycs[tt][2] * Cn]);
    const float P = sw * xv + dv;
    na += (xv - P) * P;
    da += P * P;
  }
  pna[((size_t)b * 8 + q) * Cn + c] = na;
  pda[((size_t)b * 8 + q) * Cn + c] = da;
}

// ---------------------------------------------------------------------------
// K4: reduce partials, write out. grid (q=8, b=32).
// ---------------------------------------------------------------------------
__global__ __launch_bounds__(128) void k_out(const float* __restrict__ x,
    const float* __restrict__ hh, const float* __restrict__ r_ws,
    const float* __restrict__ gamma, const float* __restrict__ pna,
    const float* __restrict__ pda, float* __restrict__ out) {
  const int q = blockIdx.x, b = blockIdx.y;
  const int tid = threadIdx.x;
  const int t0 = q * 64;
  __shared__ unsigned short cycs[64][4];

  int p0, p1, p2; float w0, w1, w2, Gv;
  topk_scan(r_ws, b, p0, p1, p2, w0, w1, w2, Gv);
  const float sw = w0 + w1 + w2;
  if (tid < 64) {
    const int t = t0 + tid;
    cycs[tid][0] = (unsigned short)(t / p0);
    cycs[tid][1] = (unsigned short)(t / p1);
    cycs[tid][2] = (unsigned short)(t / p2);
  }
  __syncthreads();

  const int c = tid;
  float num = 0.f, den = 1e-6f;
#pragma unroll
  for (int qq = 0; qq < 8; ++qq) {
    num += pna[((size_t)b * 8 + qq) * Cn + c];
    den += pda[((size_t)b * 8 + qq) * Cn + c];
  }
  const float sc = Gv * (num / den);

  const float gam = gamma[c];
  const float* hh0 = hh + ((size_t)(b * 3 + 0) * CYC) * Cn + c;
  const float* hh1 = hh + ((size_t)(b * 3 + 1) * CYC) * Cn + c;
  const float* hh2 = hh + ((size_t)(b * 3 + 2) * CYC) * Cn + c;
  const float* xb = x + (size_t)b * Tn * Cn;
  float* ob = out + (size_t)b * Tn * Cn;

  for (int tt = 0; tt < 64; ++tt) {
    const int t = t0 + tt;
    const float xv = xb[t * Cn + c];
    const float dv = gam * (w0 * hh0[cycs[tt][0] * Cn] +
                            w1 * hh1[cycs[tt][1] * Cn] +
                            w2 * hh2[cycs[tt][2] * Cn]);
    const float P = sw * xv + dv;
    ob[t * Cn + c] = xv - sc * P;
  }
}

// ---------------------------------------------------------------------------
extern "C" void kernel_launch(void* const* d_in, const int* in_sizes, int n_in,
                              void* d_out, int out_size, void* d_ws, size_t ws_size,
                              hipStream_t stream) {
  const float* x     = (const float*)d_in[0];
  const float* Wdw   = (const float*)d_in[1];
  const float* Wpw   = (const float*)d_in[2];
  const float* gnw   = (const float*)d_in[3];
  const float* gnb   = (const float*)d_in[4];
  const float* Wgate = (const float*)d_in[5];
  const float* gamma = (const float*)d_in[6];
  float* out = (float*)d_out;

  char* ws = (char*)d_ws;
  float* r_ws = (float*)ws;                       // 32*4*57 floats (~29 KB)
  float* pna  = (float*)(ws + 65536);             // 32*8*128 floats (128 KB)
  float* pda  = (float*)(ws + 65536 + 131072);    // 128 KB
  float* hh   = (float*)(ws + 1048576);           // 96*64*128 floats (3 MB)

  k_autocorr<<<Bn * 32, 256, 0, stream>>>(x, r_ws);
  k_foldconv<<<dim3(Bn * Kk, 2), 512, 0, stream>>>(x, r_ws, Wdw, Wpw, gnw, gnb, Wgate, hh);
  k_dot<<<dim3(8, Bn), 128, 0, stream>>>(x, hh, r_ws, gamma, pna, pda);
  k_out<<<dim3(8, Bn), 128, 0, stream>>>(x, hh, r_ws, gamma, pna, pda, out);
}